// Round 3
// baseline (464.583 us; speedup 1.0000x reference)
//
#include <hip/hip_runtime.h>

#define FEAT 128
#define HID 32
#define EMB 16
#define NEG 0.2f

// CSR-build binning parameters. Assumes Nn <= 2^17 (src id fits 17 bits) and
// Nn <= NBMAX*BIN_NODES. For this problem Nn=100000, E=3.2M.
#define BSH 8                 // 256 nodes per bin
#define BIN_NODES 256
#define NBMAX 400             // >= ceil(100000/256)=391
#define CH 8192               // edges per partition block
#define CAP 12288             // LDS staging capacity per bin (mean 8192, +45 sigma)
#define SRCBITS 17
#define SRCMASK 0x1FFFF

__device__ __forceinline__ float lrelu(float a) { return a > 0.0f ? a : NEG * a; }

__global__ __launch_bounds__(256) void k_zero_int(int* p, int n) {
    int i = (int)(blockIdx.x * 256 + threadIdx.x);
    if (i < n) p[i] = 0;
}

// ---- CSR build, phase 1: per-bin edge counts (dst >> BSH) ----
__global__ __launch_bounds__(256) void k_bincnt(const int* __restrict__ ei, int E_,
                                                int Nn, int* __restrict__ binCnt) {
    __shared__ int h[NBMAX];
    int nb = (Nn + BIN_NODES - 1) >> BSH;
    for (int i = threadIdx.x; i < nb; i += 256) h[i] = 0;
    __syncthreads();
    int stride = (int)(gridDim.x * 256);
    for (int i = (int)(blockIdx.x * 256 + threadIdx.x); i < E_; i += stride)
        atomicAdd(&h[ei[(size_t)E_ + i] >> BSH], 1);
    __syncthreads();
    for (int i = threadIdx.x; i < nb; i += 256)
        if (h[i]) atomicAdd(&binCnt[i], h[i]);
}

// ---- phase 2: scan bin counts -> binstart, init bin_pos; rowptr[Nn]=E ----
__global__ __launch_bounds__(512) void k_binscan(const int* __restrict__ binCnt,
                                                 int* __restrict__ binstart,
                                                 int* __restrict__ bin_pos,
                                                 int* __restrict__ rowptr,
                                                 int Nn, int E_) {
    __shared__ int s[512];
    int nb = (Nn + BIN_NODES - 1) >> BSH;
    int t = (int)threadIdx.x;
    s[t] = (t < nb) ? binCnt[t] : 0;
    __syncthreads();
    for (int off = 1; off < 512; off <<= 1) {
        int v = (t >= off) ? s[t - off] : 0;
        __syncthreads();
        s[t] += v;
        __syncthreads();
    }
    if (t <= nb) binstart[t] = (t == 0) ? 0 : s[t - 1];
    if (t < nb) bin_pos[t] = (t == 0) ? 0 : s[t - 1];
    if (t == 0) rowptr[Nn] = E_;
}

// ---- phase 3: multisplit partition. Stage chunk in LDS grouped by bin, then
// write contiguous per-bin runs of packed words ((dst&255)<<17 | src). ----
__global__ __launch_bounds__(1024) void k_part(const int* __restrict__ ei, int E_,
                                               int Nn, int* __restrict__ bin_pos,
                                               int* __restrict__ packed) {
    __shared__ int hist[NBMAX];
    __shared__ int lofs[NBMAX];
    __shared__ int pos[NBMAX];
    __shared__ int gbase[NBMAX];
    __shared__ int sscan[512];
    __shared__ int staged[CH];
    __shared__ unsigned short sbin[CH];
    int nb = (Nn + BIN_NODES - 1) >> BSH;
    int base = (int)(blockIdx.x * CH);
    int nE = min(CH, E_ - base);
    int t = (int)threadIdx.x;
    for (int i = t; i < nb; i += 1024) hist[i] = 0;
    __syncthreads();

    int myw[CH / 1024];
    int myb[CH / 1024];
#pragma unroll
    for (int k = 0; k < CH / 1024; ++k) {
        int i = t + k * 1024;
        int w = 0, b_ = -1;
        if (i < nE) {
            int s_ = ei[base + i];
            int d_ = ei[(size_t)E_ + base + i];
            b_ = d_ >> BSH;
            w = ((d_ & (BIN_NODES - 1)) << SRCBITS) | s_;
            atomicAdd(&hist[b_], 1);
        }
        myw[k] = w;
        myb[k] = b_;
    }
    __syncthreads();
    // exclusive scan of hist over 512-wide region
    if (t < 512) sscan[t] = (t < nb) ? hist[t] : 0;
    __syncthreads();
    for (int off = 1; off < 512; off <<= 1) {
        int v = 0;
        if (t < 512 && t >= off) v = sscan[t - off];
        __syncthreads();
        if (t < 512) sscan[t] += v;
        __syncthreads();
    }
    for (int i = t; i < nb; i += 1024) {
        int ex = (i == 0) ? 0 : sscan[i - 1];
        lofs[i] = ex;
        pos[i] = ex;
    }
    __syncthreads();
    // scatter into LDS grouped by bin
#pragma unroll
    for (int k = 0; k < CH / 1024; ++k) {
        if (myb[k] >= 0) {
            int p = atomicAdd(&pos[myb[k]], 1);
            staged[p] = myw[k];
            sbin[p] = (unsigned short)myb[k];
        }
    }
    __syncthreads();
    // reserve global runs (one atomic per non-empty bin)
    for (int i = t; i < nb; i += 1024)
        gbase[i] = hist[i] ? atomicAdd(&bin_pos[i], hist[i]) : 0;
    __syncthreads();
    // coalesced write-out of per-bin runs
    for (int i = t; i < nE; i += 1024) {
        int b_ = sbin[i];
        packed[gbase[b_] + (i - lofs[b_])] = staged[i];
    }
}

// ---- phase 4: per-bin build. LDS scatter -> coalesced CSR (in place over
// packed), and writes the bin's slice of rowptr. scratch = h1 buffer (free
// until k_h1 runs) used only in the (statistically impossible) overflow path.
__global__ __launch_bounds__(1024) void k_build(const int* __restrict__ binstart,
                                                int Nn, int E_,
                                                int* __restrict__ packed,
                                                int* __restrict__ rowptr,
                                                int* __restrict__ scratch) {
    __shared__ int ncnt[BIN_NODES];
    __shared__ int npos[BIN_NODES];
    __shared__ int sscan[BIN_NODES];
    __shared__ int csr_l[CAP];
    int b = (int)blockIdx.x;
    int s = binstart[b], e = binstart[b + 1];
    int cnt = e - s;
    int nb0 = b << BSH;
    int nodes = min(BIN_NODES, Nn - nb0);
    int t = (int)threadIdx.x;
    if (t < BIN_NODES) ncnt[t] = 0;
    __syncthreads();
    for (int i = t; i < cnt; i += 1024) atomicAdd(&ncnt[packed[s + i] >> SRCBITS], 1);
    __syncthreads();
    if (t < BIN_NODES) sscan[t] = ncnt[t];
    __syncthreads();
    for (int off = 1; off < BIN_NODES; off <<= 1) {
        int v = 0;
        if (t < BIN_NODES && t >= off) v = sscan[t - off];
        __syncthreads();
        if (t < BIN_NODES) sscan[t] += v;
        __syncthreads();
    }
    if (t < BIN_NODES) {
        int ex = (t == 0) ? 0 : sscan[t - 1];
        npos[t] = ex;
        if (t < nodes) rowptr[nb0 + t] = s + ex;
    }
    __syncthreads();
    if (cnt <= CAP) {
        for (int i = t; i < cnt; i += 1024) {
            int w = packed[s + i];
            int p = atomicAdd(&npos[w >> SRCBITS], 1);
            csr_l[p] = w & SRCMASK;
        }
        __syncthreads();
        for (int i = t; i < cnt; i += 1024) packed[s + i] = csr_l[i];
    } else {
        // overflow fallback: stage via global scratch, then in-place scatter
        for (int i = t; i < cnt; i += 1024) scratch[s + i] = packed[s + i];
        __syncthreads();
        for (int i = t; i < cnt; i += 1024) {
            int w = scratch[s + i];
            int p = atomicAdd(&npos[w >> SRCBITS], 1);
            packed[s + p] = w & SRCMASK;
        }
    }
}

// h1 = x @ W1 ; als/ald.  W1 transposed+XOR-swizzled in LDS so each lane does
// one conflict-free ds_read_b128 per k4; each lane computes 2 rows (4/wave)
// with 4 independent partial sums per row.
__global__ __launch_bounds__(256) void k_h1(
    const float* __restrict__ x, const float* __restrict__ W1,
    const float* __restrict__ a_s, const float* __restrict__ a_d,
    float* __restrict__ h1, float* __restrict__ als, float* __restrict__ ald, int Nn)
{
    __shared__ float Wl[HID * FEAT];           // 16 KB, col-major + granule swizzle
    for (int i = threadIdx.x; i < FEAT * HID; i += 256) {
        int k = i >> 5, c = i & 31;            // W1[k][c]
        int k4 = k >> 2, j = k & 3;
        Wl[c * FEAT + ((k4 ^ (c & 7)) << 2) + j] = W1[i];
    }
    __syncthreads();
    int wid = (int)(threadIdx.x >> 6);
    int lane = (int)(threadIdx.x & 63);
    int half = lane >> 5;
    int c = lane & 31;
    int r0 = (int)blockIdx.x * 16 + wid * 4 + half * 2;
    int r1 = r0 + 1;
    bool v0 = r0 < Nn, v1 = r1 < Nn;
    const float asv = a_s[c], adv = a_d[c];
    const float4* Wr = (const float4*)&Wl[c * FEAT];
    const float4* x0 = (const float4*)(x + (size_t)(v0 ? r0 : 0) * FEAT);
    const float4* x1 = (const float4*)(x + (size_t)(v1 ? r1 : 0) * FEAT);
    float a00 = 0, a01 = 0, a02 = 0, a03 = 0;
    float a10 = 0, a11 = 0, a12 = 0, a13 = 0;
    int sw = c & 7;
#pragma unroll
    for (int k4 = 0; k4 < FEAT / 4; ++k4) {
        float4 wv = Wr[k4 ^ sw];
        float4 xa = x0[k4];
        float4 xb = x1[k4];
        a00 += xa.x * wv.x; a01 += xa.y * wv.y;
        a02 += xa.z * wv.z; a03 += xa.w * wv.w;
        a10 += xb.x * wv.x; a11 += xb.y * wv.y;
        a12 += xb.z * wv.z; a13 += xb.w * wv.w;
    }
    float acc0 = (a00 + a01) + (a02 + a03);
    float acc1 = (a10 + a11) + (a12 + a13);
    if (v0) h1[(size_t)r0 * HID + c] = acc0;
    if (v1) h1[(size_t)r1 * HID + c] = acc1;
    float p0s = acc0 * asv, p0d = acc0 * adv;
    float p1s = acc1 * asv, p1d = acc1 * adv;
    for (int m = 1; m < 32; m <<= 1) {
        p0s += __shfl_xor(p0s, m, 32);
        p0d += __shfl_xor(p0d, m, 32);
        p1s += __shfl_xor(p1s, m, 32);
        p1d += __shfl_xor(p1d, m, 32);
    }
    if (c == 0) {
        if (v0) { als[r0] = p0s; ald[r0] = p0d; }
        if (v1) { als[r1] = p1s; ald[r1] = p1d; }
    }
}

// layer-1 gather-aggregate + norm + relu + (g @ W2) + als2/ald2, fused.
// 32 lanes per node. Edge weights computed ONCE per edge (lane e owns edge e
// of each 32-chunk, coalesced csr/als loads), then broadcast via shfl; feature
// accumulation uses 4 independent partial sums.
__global__ __launch_bounds__(256) void k_agg1(
    const int* __restrict__ rowptr, const int* __restrict__ csr_src,
    const float* __restrict__ h1, const float* __restrict__ als,
    const float* __restrict__ ald, const float* __restrict__ b1,
    const float* __restrict__ W2, const float* __restrict__ a_s2,
    const float* __restrict__ a_d2,
    float* __restrict__ h2, float* __restrict__ als2, float* __restrict__ ald2, int Nn)
{
    int n = (int)(blockIdx.x * 8 + (threadIdx.x >> 5));
    if (n >= Nn) return;
    int t = threadIdx.x & 31;
    float aldn = ald[n];
    // self-loop
    float wself = __expf(lrelu(als[n] + aldn));
    float sum0 = wself * h1[(size_t)n * HID + t];
    float sum1 = 0.0f, sum2 = 0.0f, sum3 = 0.0f;
    float denl = (t == 0) ? wself : 0.0f;
    int e0 = rowptr[n], e1 = rowptr[n + 1];
    for (int base = e0; base < e1; base += 32) {
        int rem = e1 - base;
        int s = 0;
        float wv = 0.0f;
        if (t < rem) {
            s = csr_src[base + t];
            wv = __expf(lrelu(als[s] + aldn));
            denl += wv;
        }
        if (rem >= 32) {
#pragma unroll
            for (int ee = 0; ee < 32; ee += 4) {
                int s0 = __shfl(s, ee + 0, 32);  float w0 = __shfl(wv, ee + 0, 32);
                int s1 = __shfl(s, ee + 1, 32);  float w1 = __shfl(wv, ee + 1, 32);
                int s2 = __shfl(s, ee + 2, 32);  float w2 = __shfl(wv, ee + 2, 32);
                int s3 = __shfl(s, ee + 3, 32);  float w3 = __shfl(wv, ee + 3, 32);
                sum0 += w0 * h1[(size_t)(s0 * HID + t)];
                sum1 += w1 * h1[(size_t)(s1 * HID + t)];
                sum2 += w2 * h1[(size_t)(s2 * HID + t)];
                sum3 += w3 * h1[(size_t)(s3 * HID + t)];
            }
        } else {
            for (int ee = 0; ee < rem; ++ee) {
                int se = __shfl(s, ee, 32);
                float we = __shfl(wv, ee, 32);
                sum0 += we * h1[(size_t)(se * HID + t)];
            }
        }
    }
    float sum = (sum0 + sum1) + (sum2 + sum3);
    float den = denl;
    for (int m = 1; m < 32; m <<= 1) den += __shfl_xor(den, m, 32);
    float g = fmaxf(sum / den + b1[t], 0.0f);
    // h2[n][j] = sum_t g[t] * W2[t][j];  j duplicated across both 16-halves
    int j = t & 15;
    float hc = 0.0f;
#pragma unroll
    for (int tt = 0; tt < HID; ++tt)
        hc += __shfl(g, tt, 32) * W2[tt * EMB + j];
    if (t < 16) h2[(size_t)n * EMB + j] = hc;
    float ps = hc * a_s2[j], pd = hc * a_d2[j];
    for (int m = 1; m < 16; m <<= 1) {
        ps += __shfl_xor(ps, m, 16);
        pd += __shfl_xor(pd, m, 16);
    }
    if (t == 0) { als2[n] = ps; ald2[n] = pd; }
}

// layer-2 gather-aggregate + bias. 16 lanes per node, same weight-dedup scheme
// with 16-edge chunks.
__global__ __launch_bounds__(256) void k_agg2(
    const int* __restrict__ rowptr, const int* __restrict__ csr_src,
    const float* __restrict__ h2, const float* __restrict__ als,
    const float* __restrict__ ald, const float* __restrict__ b2,
    float* __restrict__ out, int Nn)
{
    int n = (int)(blockIdx.x * 16 + (threadIdx.x >> 4));
    if (n >= Nn) return;
    int t = threadIdx.x & 15;
    float aldn = ald[n];
    float wself = __expf(lrelu(als[n] + aldn));
    float sum0 = wself * h2[(size_t)n * EMB + t];
    float sum1 = 0.0f, sum2 = 0.0f, sum3 = 0.0f;
    float denl = (t == 0) ? wself : 0.0f;
    int e0 = rowptr[n], e1 = rowptr[n + 1];
    for (int base = e0; base < e1; base += 16) {
        int rem = e1 - base;
        int s = 0;
        float wv = 0.0f;
        if (t < rem) {
            s = csr_src[base + t];
            wv = __expf(lrelu(als[s] + aldn));
            denl += wv;
        }
        if (rem >= 16) {
#pragma unroll
            for (int ee = 0; ee < 16; ee += 4) {
                int s0 = __shfl(s, ee + 0, 16);  float w0 = __shfl(wv, ee + 0, 16);
                int s1 = __shfl(s, ee + 1, 16);  float w1 = __shfl(wv, ee + 1, 16);
                int s2 = __shfl(s, ee + 2, 16);  float w2 = __shfl(wv, ee + 2, 16);
                int s3 = __shfl(s, ee + 3, 16);  float w3 = __shfl(wv, ee + 3, 16);
                sum0 += w0 * h2[(size_t)(s0 * EMB + t)];
                sum1 += w1 * h2[(size_t)(s1 * EMB + t)];
                sum2 += w2 * h2[(size_t)(s2 * EMB + t)];
                sum3 += w3 * h2[(size_t)(s3 * EMB + t)];
            }
        } else {
            for (int ee = 0; ee < rem; ++ee) {
                int se = __shfl(s, ee, 16);
                float we = __shfl(wv, ee, 16);
                sum0 += we * h2[(size_t)(se * EMB + t)];
            }
        }
    }
    float sum = (sum0 + sum1) + (sum2 + sum3);
    float den = denl;
    for (int m = 1; m < 16; m <<= 1) den += __shfl_xor(den, m, 16);
    out[(size_t)n * EMB + t] = sum / den + b2[t];
}

extern "C" void kernel_launch(void* const* d_in, const int* in_sizes, int n_in,
                              void* d_out, int out_size, void* d_ws, size_t ws_size,
                              hipStream_t stream)
{
    const float* x   = (const float*)d_in[0];
    const int*   ei  = (const int*)d_in[1];
    // d_in[2] = ew, unused (edge_dim=None)
    const float* W1  = (const float*)d_in[3];
    const float* as1 = (const float*)d_in[4];
    const float* ad1 = (const float*)d_in[5];
    const float* b1  = (const float*)d_in[6];
    const float* W2  = (const float*)d_in[7];
    const float* as2 = (const float*)d_in[8];
    const float* ad2 = (const float*)d_in[9];
    const float* b2  = (const float*)d_in[10];
    float* out = (float*)d_out;

    const int Nn = in_sizes[0] / FEAT;   // 100000
    const int E_ = in_sizes[1] / 2;      // 3200000
    const int nb = (Nn + BIN_NODES - 1) >> BSH;   // 391

    // workspace layout
    float* h1    = (float*)d_ws;                  // Nn*32 (also CSR-build scratch)
    float* als1  = h1 + (size_t)Nn * HID;         // Nn
    float* ald1  = als1 + Nn;                     // Nn
    float* h2    = ald1 + Nn;                     // Nn*16
    float* als2p = h2 + (size_t)Nn * EMB;         // Nn
    float* ald2p = als2p + Nn;                    // Nn
    int* rowptr  = (int*)(ald2p + Nn);            // Nn+1
    int* binCnt  = rowptr + Nn + 1;               // NBMAX
    int* binstart= binCnt + NBMAX;                // NBMAX+1
    int* bin_pos = binstart + NBMAX + 1;          // NBMAX
    int* packed  = bin_pos + NBMAX;               // E_  (becomes csr_src in place)
    // total: 52*Nn floats + (Nn+1+3*NBMAX+1+E_) ints ~= 34 MB

    // ---- build CSR (by destination) via binned counting sort ----
    k_zero_int<<<(nb + 255) / 256, 256, 0, stream>>>(binCnt, nb);
    k_bincnt<<<1024, 256, 0, stream>>>(ei, E_, Nn, binCnt);
    k_binscan<<<1, 512, 0, stream>>>(binCnt, binstart, bin_pos, rowptr, Nn, E_);
    k_part<<<(E_ + CH - 1) / CH, 1024, 0, stream>>>(ei, E_, Nn, bin_pos, packed);
    k_build<<<nb, 1024, 0, stream>>>(binstart, Nn, E_, packed, rowptr, (int*)h1);

    // ---- layer 1 ----
    k_h1<<<(Nn + 15) / 16, 256, 0, stream>>>(x, W1, as1, ad1, h1, als1, ald1, Nn);
    k_agg1<<<(Nn + 7) / 8, 256, 0, stream>>>(rowptr, packed, h1, als1, ald1,
                                             b1, W2, as2, ad2, h2, als2p, ald2p, Nn);
    // ---- layer 2 ----
    k_agg2<<<(Nn + 15) / 16, 256, 0, stream>>>(rowptr, packed, h2, als2p, ald2p,
                                               b2, out, Nn);
}

// Round 4
// 392.161 us; speedup vs baseline: 1.1847x; 1.1847x over previous
//
#include <hip/hip_runtime.h>

#define FEAT 128
#define HID 32
#define EMB 16
#define NEG 0.2f

// CSR-build binning parameters. Assumes Nn <= 2^17 (src id fits 17 bits) and
// Nn <= NBMAX*BIN_NODES. For this problem Nn=100000, E=3.2M.
#define BSH 8                 // 256 nodes per bin
#define BIN_NODES 256
#define NBMAX 400             // >= ceil(100000/256)=391
#define CH 8192               // edges per partition block
#define CAP 12288             // LDS staging capacity per bin (mean 8192, +45 sigma)
#define SRCBITS 17
#define SRCMASK 0x1FFFF

__device__ __forceinline__ float lrelu(float a) { return a > 0.0f ? a : NEG * a; }

__global__ __launch_bounds__(256) void k_zero_int(int* p, int n) {
    int i = (int)(blockIdx.x * 256 + threadIdx.x);
    if (i < n) p[i] = 0;
}

// ---- CSR build, phase 1: per-bin edge counts (dst >> BSH) ----
__global__ __launch_bounds__(256) void k_bincnt(const int* __restrict__ ei, int E_,
                                                int Nn, int* __restrict__ binCnt) {
    __shared__ int h[NBMAX];
    int nb = (Nn + BIN_NODES - 1) >> BSH;
    for (int i = threadIdx.x; i < nb; i += 256) h[i] = 0;
    __syncthreads();
    int stride = (int)(gridDim.x * 256);
    for (int i = (int)(blockIdx.x * 256 + threadIdx.x); i < E_; i += stride)
        atomicAdd(&h[ei[(size_t)E_ + i] >> BSH], 1);
    __syncthreads();
    for (int i = threadIdx.x; i < nb; i += 256)
        if (h[i]) atomicAdd(&binCnt[i], h[i]);
}

// ---- phase 2: scan bin counts -> binstart, init bin_pos; rowptr[Nn]=E ----
__global__ __launch_bounds__(512) void k_binscan(const int* __restrict__ binCnt,
                                                 int* __restrict__ binstart,
                                                 int* __restrict__ bin_pos,
                                                 int* __restrict__ rowptr,
                                                 int Nn, int E_) {
    __shared__ int s[512];
    int nb = (Nn + BIN_NODES - 1) >> BSH;
    int t = (int)threadIdx.x;
    s[t] = (t < nb) ? binCnt[t] : 0;
    __syncthreads();
    for (int off = 1; off < 512; off <<= 1) {
        int v = (t >= off) ? s[t - off] : 0;
        __syncthreads();
        s[t] += v;
        __syncthreads();
    }
    if (t <= nb) binstart[t] = (t == 0) ? 0 : s[t - 1];
    if (t < nb) bin_pos[t] = (t == 0) ? 0 : s[t - 1];
    if (t == 0) rowptr[Nn] = E_;
}

// ---- phase 3: multisplit partition. Stage chunk in LDS grouped by bin, then
// write contiguous per-bin runs of packed words ((dst&255)<<17 | src). ----
__global__ __launch_bounds__(1024) void k_part(const int* __restrict__ ei, int E_,
                                               int Nn, int* __restrict__ bin_pos,
                                               int* __restrict__ packed) {
    __shared__ int hist[NBMAX];
    __shared__ int lofs[NBMAX];
    __shared__ int pos[NBMAX];
    __shared__ int gbase[NBMAX];
    __shared__ int sscan[512];
    __shared__ int staged[CH];
    __shared__ unsigned short sbin[CH];
    int nb = (Nn + BIN_NODES - 1) >> BSH;
    int base = (int)(blockIdx.x * CH);
    int nE = min(CH, E_ - base);
    int t = (int)threadIdx.x;
    for (int i = t; i < nb; i += 1024) hist[i] = 0;
    __syncthreads();

    int myw[CH / 1024];
    int myb[CH / 1024];
#pragma unroll
    for (int k = 0; k < CH / 1024; ++k) {
        int i = t + k * 1024;
        int w = 0, b_ = -1;
        if (i < nE) {
            int s_ = ei[base + i];
            int d_ = ei[(size_t)E_ + base + i];
            b_ = d_ >> BSH;
            w = ((d_ & (BIN_NODES - 1)) << SRCBITS) | s_;
            atomicAdd(&hist[b_], 1);
        }
        myw[k] = w;
        myb[k] = b_;
    }
    __syncthreads();
    // exclusive scan of hist over 512-wide region
    if (t < 512) sscan[t] = (t < nb) ? hist[t] : 0;
    __syncthreads();
    for (int off = 1; off < 512; off <<= 1) {
        int v = 0;
        if (t < 512 && t >= off) v = sscan[t - off];
        __syncthreads();
        if (t < 512) sscan[t] += v;
        __syncthreads();
    }
    for (int i = t; i < nb; i += 1024) {
        int ex = (i == 0) ? 0 : sscan[i - 1];
        lofs[i] = ex;
        pos[i] = ex;
    }
    __syncthreads();
    // scatter into LDS grouped by bin
#pragma unroll
    for (int k = 0; k < CH / 1024; ++k) {
        if (myb[k] >= 0) {
            int p = atomicAdd(&pos[myb[k]], 1);
            staged[p] = myw[k];
            sbin[p] = (unsigned short)myb[k];
        }
    }
    __syncthreads();
    // reserve global runs (one atomic per non-empty bin)
    for (int i = t; i < nb; i += 1024)
        gbase[i] = hist[i] ? atomicAdd(&bin_pos[i], hist[i]) : 0;
    __syncthreads();
    // coalesced write-out of per-bin runs
    for (int i = t; i < nE; i += 1024) {
        int b_ = sbin[i];
        packed[gbase[b_] + (i - lofs[b_])] = staged[i];
    }
}

// ---- phase 4: per-bin build. LDS scatter -> coalesced CSR (in place over
// packed), and writes the bin's slice of rowptr. scratch = h1 buffer (free
// until k_h1 runs) used only in the (statistically impossible) overflow path.
__global__ __launch_bounds__(1024) void k_build(const int* __restrict__ binstart,
                                                int Nn, int E_,
                                                int* __restrict__ packed,
                                                int* __restrict__ rowptr,
                                                int* __restrict__ scratch) {
    __shared__ int ncnt[BIN_NODES];
    __shared__ int npos[BIN_NODES];
    __shared__ int sscan[BIN_NODES];
    __shared__ int csr_l[CAP];
    int b = (int)blockIdx.x;
    int s = binstart[b], e = binstart[b + 1];
    int cnt = e - s;
    int nb0 = b << BSH;
    int nodes = min(BIN_NODES, Nn - nb0);
    int t = (int)threadIdx.x;
    if (t < BIN_NODES) ncnt[t] = 0;
    __syncthreads();
    for (int i = t; i < cnt; i += 1024) atomicAdd(&ncnt[packed[s + i] >> SRCBITS], 1);
    __syncthreads();
    if (t < BIN_NODES) sscan[t] = ncnt[t];
    __syncthreads();
    for (int off = 1; off < BIN_NODES; off <<= 1) {
        int v = 0;
        if (t < BIN_NODES && t >= off) v = sscan[t - off];
        __syncthreads();
        if (t < BIN_NODES) sscan[t] += v;
        __syncthreads();
    }
    if (t < BIN_NODES) {
        int ex = (t == 0) ? 0 : sscan[t - 1];
        npos[t] = ex;
        if (t < nodes) rowptr[nb0 + t] = s + ex;
    }
    __syncthreads();
    if (cnt <= CAP) {
        for (int i = t; i < cnt; i += 1024) {
            int w = packed[s + i];
            int p = atomicAdd(&npos[w >> SRCBITS], 1);
            csr_l[p] = w & SRCMASK;
        }
        __syncthreads();
        for (int i = t; i < cnt; i += 1024) packed[s + i] = csr_l[i];
    } else {
        // overflow fallback: stage via global scratch, then in-place scatter
        for (int i = t; i < cnt; i += 1024) scratch[s + i] = packed[s + i];
        __syncthreads();
        for (int i = t; i < cnt; i += 1024) {
            int w = scratch[s + i];
            int p = atomicAdd(&npos[w >> SRCBITS], 1);
            packed[s + p] = w & SRCMASK;
        }
    }
}

// h1 = x @ W1 ; als/ald.  W1 transposed+XOR-swizzled in LDS so each lane does
// one conflict-free ds_read_b128 per k4; each lane computes 2 rows (4/wave)
// with 4 independent partial sums per row.
__global__ __launch_bounds__(256) void k_h1(
    const float* __restrict__ x, const float* __restrict__ W1,
    const float* __restrict__ a_s, const float* __restrict__ a_d,
    float* __restrict__ h1, float* __restrict__ als, float* __restrict__ ald, int Nn)
{
    __shared__ float Wl[HID * FEAT];           // 16 KB, col-major + granule swizzle
    for (int i = threadIdx.x; i < FEAT * HID; i += 256) {
        int k = i >> 5, c = i & 31;            // W1[k][c]
        int k4 = k >> 2, j = k & 3;
        Wl[c * FEAT + ((k4 ^ (c & 7)) << 2) + j] = W1[i];
    }
    __syncthreads();
    int wid = (int)(threadIdx.x >> 6);
    int lane = (int)(threadIdx.x & 63);
    int half = lane >> 5;
    int c = lane & 31;
    int r0 = (int)blockIdx.x * 16 + wid * 4 + half * 2;
    int r1 = r0 + 1;
    bool v0 = r0 < Nn, v1 = r1 < Nn;
    const float asv = a_s[c], adv = a_d[c];
    const float4* Wr = (const float4*)&Wl[c * FEAT];
    const float4* x0 = (const float4*)(x + (size_t)(v0 ? r0 : 0) * FEAT);
    const float4* x1 = (const float4*)(x + (size_t)(v1 ? r1 : 0) * FEAT);
    float a00 = 0, a01 = 0, a02 = 0, a03 = 0;
    float a10 = 0, a11 = 0, a12 = 0, a13 = 0;
    int sw = c & 7;
#pragma unroll
    for (int k4 = 0; k4 < FEAT / 4; ++k4) {
        float4 wv = Wr[k4 ^ sw];
        float4 xa = x0[k4];
        float4 xb = x1[k4];
        a00 += xa.x * wv.x; a01 += xa.y * wv.y;
        a02 += xa.z * wv.z; a03 += xa.w * wv.w;
        a10 += xb.x * wv.x; a11 += xb.y * wv.y;
        a12 += xb.z * wv.z; a13 += xb.w * wv.w;
    }
    float acc0 = (a00 + a01) + (a02 + a03);
    float acc1 = (a10 + a11) + (a12 + a13);
    if (v0) h1[(size_t)r0 * HID + c] = acc0;
    if (v1) h1[(size_t)r1 * HID + c] = acc1;
    float p0s = acc0 * asv, p0d = acc0 * adv;
    float p1s = acc1 * asv, p1d = acc1 * adv;
    for (int m = 1; m < 32; m <<= 1) {
        p0s += __shfl_xor(p0s, m, 32);
        p0d += __shfl_xor(p0d, m, 32);
        p1s += __shfl_xor(p1s, m, 32);
        p1d += __shfl_xor(p1d, m, 32);
    }
    if (c == 0) {
        if (v0) { als[r0] = p0s; ald[r0] = p0d; }
        if (v1) { als[r1] = p1s; ald[r1] = p1d; }
    }
}

// layer-1 gather-aggregate + norm + relu + (g @ W2) + als2/ald2, fused.
// 16 lanes per node, each lane owns 2 features (float2). Edge loop unrolled
// 4x: four independent gather chains in flight; edge weights computed
// redundantly per lane (identical across group -> den needs no reduction).
__global__ __launch_bounds__(256) void k_agg1(
    const int* __restrict__ rowptr, const int* __restrict__ csr_src,
    const float* __restrict__ h1, const float* __restrict__ als,
    const float* __restrict__ ald, const float* __restrict__ b1,
    const float* __restrict__ W2, const float* __restrict__ a_s2,
    const float* __restrict__ a_d2,
    float* __restrict__ h2, float* __restrict__ als2, float* __restrict__ ald2, int Nn)
{
    int n = (int)(blockIdx.x * 16 + (threadIdx.x >> 4));
    if (n >= Nn) return;
    int l = threadIdx.x & 15;                  // lane in 16-lane group
    const float2* h1p = (const float2*)h1;     // row s = elems [s*16 .. s*16+15]
    float aldn = ald[n];
    float wself = __expf(lrelu(als[n] + aldn));
    float2 sv = h1p[(size_t)n * 16 + l];
    float s0x = wself * sv.x, s0y = wself * sv.y;
    float s1x = 0, s1y = 0, s2x = 0, s2y = 0, s3x = 0, s3y = 0;
    float den = wself;
    int e = rowptr[n], e1 = rowptr[n + 1];
    for (; e + 4 <= e1; e += 4) {
        int i0 = csr_src[e + 0];
        int i1 = csr_src[e + 1];
        int i2 = csr_src[e + 2];
        int i3 = csr_src[e + 3];
        float2 f0 = h1p[(size_t)i0 * 16 + l];
        float2 f1 = h1p[(size_t)i1 * 16 + l];
        float2 f2 = h1p[(size_t)i2 * 16 + l];
        float2 f3 = h1p[(size_t)i3 * 16 + l];
        float a0 = als[i0], a1 = als[i1], a2 = als[i2], a3 = als[i3];
        float w0 = __expf(lrelu(a0 + aldn));
        float w1 = __expf(lrelu(a1 + aldn));
        float w2 = __expf(lrelu(a2 + aldn));
        float w3 = __expf(lrelu(a3 + aldn));
        s0x += w0 * f0.x; s0y += w0 * f0.y;
        s1x += w1 * f1.x; s1y += w1 * f1.y;
        s2x += w2 * f2.x; s2y += w2 * f2.y;
        s3x += w3 * f3.x; s3y += w3 * f3.y;
        den += (w0 + w1) + (w2 + w3);
    }
    for (; e < e1; ++e) {
        int s = csr_src[e];
        float we = __expf(lrelu(als[s] + aldn));
        float2 f = h1p[(size_t)s * 16 + l];
        s0x += we * f.x; s0y += we * f.y;
        den += we;
    }
    float inv = 1.0f / den;
    float gx = fmaxf((s0x + s1x + s2x + s3x) * inv + b1[2 * l], 0.0f);
    float gy = fmaxf((s0y + s1y + s2y + s3y) * inv + b1[2 * l + 1], 0.0f);
    // h2[n][j] = sum_t g[t] * W2[t][j], j = l; lane tt holds feats 2tt,2tt+1
    float hc = 0.0f;
#pragma unroll
    for (int tt = 0; tt < 16; ++tt) {
        float bx = __shfl(gx, tt, 16);
        float by = __shfl(gy, tt, 16);
        hc += bx * W2[(2 * tt) * EMB + l] + by * W2[(2 * tt + 1) * EMB + l];
    }
    h2[(size_t)n * EMB + l] = hc;
    float ps = hc * a_s2[l], pd = hc * a_d2[l];
    for (int m = 1; m < 16; m <<= 1) {
        ps += __shfl_xor(ps, m, 16);
        pd += __shfl_xor(pd, m, 16);
    }
    if (l == 0) { als2[n] = ps; ald2[n] = pd; }
}

// layer-2 gather-aggregate + bias. 8 lanes per node, float2 features, same
// unrolled independent-gather structure. Writes out as float2.
__global__ __launch_bounds__(256) void k_agg2(
    const int* __restrict__ rowptr, const int* __restrict__ csr_src,
    const float* __restrict__ h2, const float* __restrict__ als,
    const float* __restrict__ ald, const float* __restrict__ b2,
    float* __restrict__ out, int Nn)
{
    int n = (int)(blockIdx.x * 32 + (threadIdx.x >> 3));
    if (n >= Nn) return;
    int l = threadIdx.x & 7;                   // lane in 8-lane group
    const float2* h2p = (const float2*)h2;     // row s = elems [s*8 .. s*8+7]
    float aldn = ald[n];
    float wself = __expf(lrelu(als[n] + aldn));
    float2 sv = h2p[(size_t)n * 8 + l];
    float s0x = wself * sv.x, s0y = wself * sv.y;
    float s1x = 0, s1y = 0, s2x = 0, s2y = 0, s3x = 0, s3y = 0;
    float den = wself;
    int e = rowptr[n], e1 = rowptr[n + 1];
    for (; e + 4 <= e1; e += 4) {
        int i0 = csr_src[e + 0];
        int i1 = csr_src[e + 1];
        int i2 = csr_src[e + 2];
        int i3 = csr_src[e + 3];
        float2 f0 = h2p[(size_t)i0 * 8 + l];
        float2 f1 = h2p[(size_t)i1 * 8 + l];
        float2 f2 = h2p[(size_t)i2 * 8 + l];
        float2 f3 = h2p[(size_t)i3 * 8 + l];
        float a0 = als[i0], a1 = als[i1], a2 = als[i2], a3 = als[i3];
        float w0 = __expf(lrelu(a0 + aldn));
        float w1 = __expf(lrelu(a1 + aldn));
        float w2 = __expf(lrelu(a2 + aldn));
        float w3 = __expf(lrelu(a3 + aldn));
        s0x += w0 * f0.x; s0y += w0 * f0.y;
        s1x += w1 * f1.x; s1y += w1 * f1.y;
        s2x += w2 * f2.x; s2y += w2 * f2.y;
        s3x += w3 * f3.x; s3y += w3 * f3.y;
        den += (w0 + w1) + (w2 + w3);
    }
    for (; e < e1; ++e) {
        int s = csr_src[e];
        float we = __expf(lrelu(als[s] + aldn));
        float2 f = h2p[(size_t)s * 8 + l];
        s0x += we * f.x; s0y += we * f.y;
        den += we;
    }
    float inv = 1.0f / den;
    float2 r;
    r.x = (s0x + s1x + s2x + s3x) * inv + b2[2 * l];
    r.y = (s0y + s1y + s2y + s3y) * inv + b2[2 * l + 1];
    ((float2*)out)[(size_t)n * 8 + l] = r;
}

extern "C" void kernel_launch(void* const* d_in, const int* in_sizes, int n_in,
                              void* d_out, int out_size, void* d_ws, size_t ws_size,
                              hipStream_t stream)
{
    const float* x   = (const float*)d_in[0];
    const int*   ei  = (const int*)d_in[1];
    // d_in[2] = ew, unused (edge_dim=None)
    const float* W1  = (const float*)d_in[3];
    const float* as1 = (const float*)d_in[4];
    const float* ad1 = (const float*)d_in[5];
    const float* b1  = (const float*)d_in[6];
    const float* W2  = (const float*)d_in[7];
    const float* as2 = (const float*)d_in[8];
    const float* ad2 = (const float*)d_in[9];
    const float* b2  = (const float*)d_in[10];
    float* out = (float*)d_out;

    const int Nn = in_sizes[0] / FEAT;   // 100000
    const int E_ = in_sizes[1] / 2;      // 3200000
    const int nb = (Nn + BIN_NODES - 1) >> BSH;   // 391

    // workspace layout
    float* h1    = (float*)d_ws;                  // Nn*32 (also CSR-build scratch)
    float* als1  = h1 + (size_t)Nn * HID;         // Nn
    float* ald1  = als1 + Nn;                     // Nn
    float* h2    = ald1 + Nn;                     // Nn*16
    float* als2p = h2 + (size_t)Nn * EMB;         // Nn
    float* ald2p = als2p + Nn;                    // Nn
    int* rowptr  = (int*)(ald2p + Nn);            // Nn+1
    int* binCnt  = rowptr + Nn + 1;               // NBMAX
    int* binstart= binCnt + NBMAX;                // NBMAX+1
    int* bin_pos = binstart + NBMAX + 1;          // NBMAX
    int* packed  = bin_pos + NBMAX;               // E_  (becomes csr_src in place)
    // total: 52*Nn floats + (Nn+1+3*NBMAX+1+E_) ints ~= 34 MB

    // ---- build CSR (by destination) via binned counting sort ----
    k_zero_int<<<(nb + 255) / 256, 256, 0, stream>>>(binCnt, nb);
    k_bincnt<<<1024, 256, 0, stream>>>(ei, E_, Nn, binCnt);
    k_binscan<<<1, 512, 0, stream>>>(binCnt, binstart, bin_pos, rowptr, Nn, E_);
    k_part<<<(E_ + CH - 1) / CH, 1024, 0, stream>>>(ei, E_, Nn, bin_pos, packed);
    k_build<<<nb, 1024, 0, stream>>>(binstart, Nn, E_, packed, rowptr, (int*)h1);

    // ---- layer 1 ----
    k_h1<<<(Nn + 15) / 16, 256, 0, stream>>>(x, W1, as1, ad1, h1, als1, ald1, Nn);
    k_agg1<<<(Nn + 15) / 16, 256, 0, stream>>>(rowptr, packed, h1, als1, ald1,
                                               b1, W2, as2, ad2, h2, als2p, ald2p, Nn);
    // ---- layer 2 ----
    k_agg2<<<(Nn + 31) / 32, 256, 0, stream>>>(rowptr, packed, h2, als2p, ald2p,
                                               b2, out, Nn);
}

// Round 5
// 351.262 us; speedup vs baseline: 1.3226x; 1.1164x over previous
//
#include <hip/hip_runtime.h>

#define FEAT 128
#define HID 32
#define EMB 16
#define NEG 0.2f

// CSR-build binning parameters. Assumes Nn <= 2^17 (src id fits 17 bits) and
// Nn <= NBMAX*BIN_NODES. For this problem Nn=100000, E=3.2M.
#define BSH 8                 // 256 nodes per bin
#define BIN_NODES 256
#define NBMAX 400             // >= ceil(100000/256)=391
#define CH 8192               // edges per partition block
#define CAP 12288             // LDS staging capacity per bin (mean 8192, +45 sigma)
#define SRCBITS 17
#define SRCMASK 0x1FFFF

__device__ __forceinline__ float lrelu(float a) { return a > 0.0f ? a : NEG * a; }

__global__ __launch_bounds__(256) void k_zero_int(int* p, int n) {
    int i = (int)(blockIdx.x * 256 + threadIdx.x);
    if (i < n) p[i] = 0;
}

// ---- CSR build, phase 1: per-bin edge counts (dst >> BSH) ----
__global__ __launch_bounds__(256) void k_bincnt(const int* __restrict__ ei, int E_,
                                                int Nn, int* __restrict__ binCnt) {
    __shared__ int h[NBMAX];
    int nb = (Nn + BIN_NODES - 1) >> BSH;
    for (int i = threadIdx.x; i < nb; i += 256) h[i] = 0;
    __syncthreads();
    int stride = (int)(gridDim.x * 256);
    for (int i = (int)(blockIdx.x * 256 + threadIdx.x); i < E_; i += stride)
        atomicAdd(&h[ei[(size_t)E_ + i] >> BSH], 1);
    __syncthreads();
    for (int i = threadIdx.x; i < nb; i += 256)
        if (h[i]) atomicAdd(&binCnt[i], h[i]);
}

// ---- phase 2: scan bin counts -> binstart, init bin_pos; rowptr[Nn]=E ----
__global__ __launch_bounds__(512) void k_binscan(const int* __restrict__ binCnt,
                                                 int* __restrict__ binstart,
                                                 int* __restrict__ bin_pos,
                                                 int* __restrict__ rowptr,
                                                 int Nn, int E_) {
    __shared__ int s[512];
    int nb = (Nn + BIN_NODES - 1) >> BSH;
    int t = (int)threadIdx.x;
    s[t] = (t < nb) ? binCnt[t] : 0;
    __syncthreads();
    for (int off = 1; off < 512; off <<= 1) {
        int v = (t >= off) ? s[t - off] : 0;
        __syncthreads();
        s[t] += v;
        __syncthreads();
    }
    if (t <= nb) binstart[t] = (t == 0) ? 0 : s[t - 1];
    if (t < nb) bin_pos[t] = (t == 0) ? 0 : s[t - 1];
    if (t == 0) rowptr[Nn] = E_;
}

// ---- phase 3: multisplit partition. Stage chunk in LDS grouped by bin, then
// write contiguous per-bin runs of packed words ((dst&255)<<17 | src). ----
__global__ __launch_bounds__(1024) void k_part(const int* __restrict__ ei, int E_,
                                               int Nn, int* __restrict__ bin_pos,
                                               int* __restrict__ packed) {
    __shared__ int hist[NBMAX];
    __shared__ int lofs[NBMAX];
    __shared__ int pos[NBMAX];
    __shared__ int gbase[NBMAX];
    __shared__ int sscan[512];
    __shared__ int staged[CH];
    __shared__ unsigned short sbin[CH];
    int nb = (Nn + BIN_NODES - 1) >> BSH;
    int base = (int)(blockIdx.x * CH);
    int nE = min(CH, E_ - base);
    int t = (int)threadIdx.x;
    for (int i = t; i < nb; i += 1024) hist[i] = 0;
    __syncthreads();

    int myw[CH / 1024];
    int myb[CH / 1024];
#pragma unroll
    for (int k = 0; k < CH / 1024; ++k) {
        int i = t + k * 1024;
        int w = 0, b_ = -1;
        if (i < nE) {
            int s_ = ei[base + i];
            int d_ = ei[(size_t)E_ + base + i];
            b_ = d_ >> BSH;
            w = ((d_ & (BIN_NODES - 1)) << SRCBITS) | s_;
            atomicAdd(&hist[b_], 1);
        }
        myw[k] = w;
        myb[k] = b_;
    }
    __syncthreads();
    // exclusive scan of hist over 512-wide region
    if (t < 512) sscan[t] = (t < nb) ? hist[t] : 0;
    __syncthreads();
    for (int off = 1; off < 512; off <<= 1) {
        int v = 0;
        if (t < 512 && t >= off) v = sscan[t - off];
        __syncthreads();
        if (t < 512) sscan[t] += v;
        __syncthreads();
    }
    for (int i = t; i < nb; i += 1024) {
        int ex = (i == 0) ? 0 : sscan[i - 1];
        lofs[i] = ex;
        pos[i] = ex;
    }
    __syncthreads();
    // scatter into LDS grouped by bin
#pragma unroll
    for (int k = 0; k < CH / 1024; ++k) {
        if (myb[k] >= 0) {
            int p = atomicAdd(&pos[myb[k]], 1);
            staged[p] = myw[k];
            sbin[p] = (unsigned short)myb[k];
        }
    }
    __syncthreads();
    // reserve global runs (one atomic per non-empty bin)
    for (int i = t; i < nb; i += 1024)
        gbase[i] = hist[i] ? atomicAdd(&bin_pos[i], hist[i]) : 0;
    __syncthreads();
    // coalesced write-out of per-bin runs
    for (int i = t; i < nE; i += 1024) {
        int b_ = sbin[i];
        packed[gbase[b_] + (i - lofs[b_])] = staged[i];
    }
}

// ---- phase 4: per-bin build. LDS scatter -> coalesced CSR (in place over
// packed), and writes the bin's slice of rowptr. scratch = h1 buffer (free
// until k_h1 runs) used only in the (statistically impossible) overflow path.
__global__ __launch_bounds__(1024) void k_build(const int* __restrict__ binstart,
                                                int Nn, int E_,
                                                int* __restrict__ packed,
                                                int* __restrict__ rowptr,
                                                int* __restrict__ scratch) {
    __shared__ int ncnt[BIN_NODES];
    __shared__ int npos[BIN_NODES];
    __shared__ int sscan[BIN_NODES];
    __shared__ int csr_l[CAP];
    int b = (int)blockIdx.x;
    int s = binstart[b], e = binstart[b + 1];
    int cnt = e - s;
    int nb0 = b << BSH;
    int nodes = min(BIN_NODES, Nn - nb0);
    int t = (int)threadIdx.x;
    if (t < BIN_NODES) ncnt[t] = 0;
    __syncthreads();
    for (int i = t; i < cnt; i += 1024) atomicAdd(&ncnt[packed[s + i] >> SRCBITS], 1);
    __syncthreads();
    if (t < BIN_NODES) sscan[t] = ncnt[t];
    __syncthreads();
    for (int off = 1; off < BIN_NODES; off <<= 1) {
        int v = 0;
        if (t < BIN_NODES && t >= off) v = sscan[t - off];
        __syncthreads();
        if (t < BIN_NODES) sscan[t] += v;
        __syncthreads();
    }
    if (t < BIN_NODES) {
        int ex = (t == 0) ? 0 : sscan[t - 1];
        npos[t] = ex;
        if (t < nodes) rowptr[nb0 + t] = s + ex;
    }
    __syncthreads();
    if (cnt <= CAP) {
        for (int i = t; i < cnt; i += 1024) {
            int w = packed[s + i];
            int p = atomicAdd(&npos[w >> SRCBITS], 1);
            csr_l[p] = w & SRCMASK;
        }
        __syncthreads();
        for (int i = t; i < cnt; i += 1024) packed[s + i] = csr_l[i];
    } else {
        // overflow fallback: stage via global scratch, then in-place scatter
        for (int i = t; i < cnt; i += 1024) scratch[s + i] = packed[s + i];
        __syncthreads();
        for (int i = t; i < cnt; i += 1024) {
            int w = scratch[s + i];
            int p = atomicAdd(&npos[w >> SRCBITS], 1);
            packed[s + p] = w & SRCMASK;
        }
    }
}

// h1 = x @ W1 ; als/ald.  W1 row-major in LDS (bank = c: conflict-free scalar
// reads, other half-wave broadcasts same address). Each thread owns output
// col c and FOUR rows, so every W read feeds 4 FMAs; x loads are wave-level
// broadcasts (all lanes of a col-group read the same float4).
__global__ __launch_bounds__(256) void k_h1(
    const float* __restrict__ x, const float* __restrict__ W1,
    const float* __restrict__ a_s, const float* __restrict__ a_d,
    float* __restrict__ h1, float* __restrict__ als, float* __restrict__ ald, int Nn)
{
    __shared__ float Wl[FEAT * HID];           // 16 KB row-major
    for (int i = threadIdx.x; i < FEAT * HID; i += 256) Wl[i] = W1[i];
    __syncthreads();
    int wid = (int)(threadIdx.x >> 6);
    int lane = (int)(threadIdx.x & 63);
    int half = lane >> 5;
    int c = lane & 31;
    int r0 = (int)blockIdx.x * 32 + wid * 8 + half * 4;   // rows r0..r0+3
    bool v0 = r0 < Nn, v1 = r0 + 1 < Nn, v2 = r0 + 2 < Nn, v3 = r0 + 3 < Nn;
    const float asv = a_s[c], adv = a_d[c];
    const float4* x0 = (const float4*)(x + (size_t)(v0 ? r0 : 0) * FEAT);
    const float4* x1 = (const float4*)(x + (size_t)(v1 ? r0 + 1 : 0) * FEAT);
    const float4* x2 = (const float4*)(x + (size_t)(v2 ? r0 + 2 : 0) * FEAT);
    const float4* x3 = (const float4*)(x + (size_t)(v3 ? r0 + 3 : 0) * FEAT);
    float acc0 = 0, acc1 = 0, acc2 = 0, acc3 = 0;
#pragma unroll 2
    for (int k4 = 0; k4 < FEAT / 4; ++k4) {
        float4 xa = x0[k4];
        float4 xb = x1[k4];
        float4 xc = x2[k4];
        float4 xd = x3[k4];
        const float* wp = &Wl[k4 * 4 * HID + c];
        float w0 = wp[0], w1 = wp[HID], w2 = wp[2 * HID], w3 = wp[3 * HID];
        acc0 += xa.x * w0 + xa.y * w1 + xa.z * w2 + xa.w * w3;
        acc1 += xb.x * w0 + xb.y * w1 + xb.z * w2 + xb.w * w3;
        acc2 += xc.x * w0 + xc.y * w1 + xc.z * w2 + xc.w * w3;
        acc3 += xd.x * w0 + xd.y * w1 + xd.z * w2 + xd.w * w3;
    }
    if (v0) h1[(size_t)r0 * HID + c] = acc0;
    if (v1) h1[(size_t)(r0 + 1) * HID + c] = acc1;
    if (v2) h1[(size_t)(r0 + 2) * HID + c] = acc2;
    if (v3) h1[(size_t)(r0 + 3) * HID + c] = acc3;
    float p0s = acc0 * asv, p0d = acc0 * adv;
    float p1s = acc1 * asv, p1d = acc1 * adv;
    float p2s = acc2 * asv, p2d = acc2 * adv;
    float p3s = acc3 * asv, p3d = acc3 * adv;
    for (int m = 1; m < 32; m <<= 1) {
        p0s += __shfl_xor(p0s, m, 32);  p0d += __shfl_xor(p0d, m, 32);
        p1s += __shfl_xor(p1s, m, 32);  p1d += __shfl_xor(p1d, m, 32);
        p2s += __shfl_xor(p2s, m, 32);  p2d += __shfl_xor(p2d, m, 32);
        p3s += __shfl_xor(p3s, m, 32);  p3d += __shfl_xor(p3d, m, 32);
    }
    if (c == 0) {
        if (v0) { als[r0] = p0s;     ald[r0] = p0d; }
        if (v1) { als[r0 + 1] = p1s; ald[r0 + 1] = p1d; }
        if (v2) { als[r0 + 2] = p2s; ald[r0 + 2] = p2d; }
        if (v3) { als[r0 + 3] = p3s; ald[r0 + 3] = p3d; }
    }
}

// layer-1 gather-aggregate + norm + relu + (g @ W2) + als2/ald2, fused.
// 16 lanes per node, each lane owns 2 features (float2). Edge loop unrolled
// 4x: four independent gather chains in flight; edge weights computed
// redundantly per lane (identical across group -> den needs no reduction).
__global__ __launch_bounds__(256) void k_agg1(
    const int* __restrict__ rowptr, const int* __restrict__ csr_src,
    const float* __restrict__ h1, const float* __restrict__ als,
    const float* __restrict__ ald, const float* __restrict__ b1,
    const float* __restrict__ W2, const float* __restrict__ a_s2,
    const float* __restrict__ a_d2,
    float* __restrict__ h2, float* __restrict__ als2, float* __restrict__ ald2, int Nn)
{
    int n = (int)(blockIdx.x * 16 + (threadIdx.x >> 4));
    if (n >= Nn) return;
    int l = threadIdx.x & 15;                  // lane in 16-lane group
    const float2* h1p = (const float2*)h1;     // row s = elems [s*16 .. s*16+15]
    float aldn = ald[n];
    float wself = __expf(lrelu(als[n] + aldn));
    float2 sv = h1p[(size_t)n * 16 + l];
    float s0x = wself * sv.x, s0y = wself * sv.y;
    float s1x = 0, s1y = 0, s2x = 0, s2y = 0, s3x = 0, s3y = 0;
    float den = wself;
    int e = rowptr[n], e1 = rowptr[n + 1];
    for (; e + 4 <= e1; e += 4) {
        int i0 = csr_src[e + 0];
        int i1 = csr_src[e + 1];
        int i2 = csr_src[e + 2];
        int i3 = csr_src[e + 3];
        float2 f0 = h1p[(size_t)i0 * 16 + l];
        float2 f1 = h1p[(size_t)i1 * 16 + l];
        float2 f2 = h1p[(size_t)i2 * 16 + l];
        float2 f3 = h1p[(size_t)i3 * 16 + l];
        float a0 = als[i0], a1 = als[i1], a2 = als[i2], a3 = als[i3];
        float w0 = __expf(lrelu(a0 + aldn));
        float w1 = __expf(lrelu(a1 + aldn));
        float w2 = __expf(lrelu(a2 + aldn));
        float w3 = __expf(lrelu(a3 + aldn));
        s0x += w0 * f0.x; s0y += w0 * f0.y;
        s1x += w1 * f1.x; s1y += w1 * f1.y;
        s2x += w2 * f2.x; s2y += w2 * f2.y;
        s3x += w3 * f3.x; s3y += w3 * f3.y;
        den += (w0 + w1) + (w2 + w3);
    }
    for (; e < e1; ++e) {
        int s = csr_src[e];
        float we = __expf(lrelu(als[s] + aldn));
        float2 f = h1p[(size_t)s * 16 + l];
        s0x += we * f.x; s0y += we * f.y;
        den += we;
    }
    float inv = 1.0f / den;
    float gx = fmaxf((s0x + s1x + s2x + s3x) * inv + b1[2 * l], 0.0f);
    float gy = fmaxf((s0y + s1y + s2y + s3y) * inv + b1[2 * l + 1], 0.0f);
    // h2[n][j] = sum_t g[t] * W2[t][j], j = l; lane tt holds feats 2tt,2tt+1
    float hc = 0.0f;
#pragma unroll
    for (int tt = 0; tt < 16; ++tt) {
        float bx = __shfl(gx, tt, 16);
        float by = __shfl(gy, tt, 16);
        hc += bx * W2[(2 * tt) * EMB + l] + by * W2[(2 * tt + 1) * EMB + l];
    }
    h2[(size_t)n * EMB + l] = hc;
    float ps = hc * a_s2[l], pd = hc * a_d2[l];
    for (int m = 1; m < 16; m <<= 1) {
        ps += __shfl_xor(ps, m, 16);
        pd += __shfl_xor(pd, m, 16);
    }
    if (l == 0) { als2[n] = ps; ald2[n] = pd; }
}

// layer-2 gather-aggregate + bias. 8 lanes per node, float2 features, same
// unrolled independent-gather structure. Writes out as float2.
__global__ __launch_bounds__(256) void k_agg2(
    const int* __restrict__ rowptr, const int* __restrict__ csr_src,
    const float* __restrict__ h2, const float* __restrict__ als,
    const float* __restrict__ ald, const float* __restrict__ b2,
    float* __restrict__ out, int Nn)
{
    int n = (int)(blockIdx.x * 32 + (threadIdx.x >> 3));
    if (n >= Nn) return;
    int l = threadIdx.x & 7;                   // lane in 8-lane group
    const float2* h2p = (const float2*)h2;     // row s = elems [s*8 .. s*8+7]
    float aldn = ald[n];
    float wself = __expf(lrelu(als[n] + aldn));
    float2 sv = h2p[(size_t)n * 8 + l];
    float s0x = wself * sv.x, s0y = wself * sv.y;
    float s1x = 0, s1y = 0, s2x = 0, s2y = 0, s3x = 0, s3y = 0;
    float den = wself;
    int e = rowptr[n], e1 = rowptr[n + 1];
    for (; e + 4 <= e1; e += 4) {
        int i0 = csr_src[e + 0];
        int i1 = csr_src[e + 1];
        int i2 = csr_src[e + 2];
        int i3 = csr_src[e + 3];
        float2 f0 = h2p[(size_t)i0 * 8 + l];
        float2 f1 = h2p[(size_t)i1 * 8 + l];
        float2 f2 = h2p[(size_t)i2 * 8 + l];
        float2 f3 = h2p[(size_t)i3 * 8 + l];
        float a0 = als[i0], a1 = als[i1], a2 = als[i2], a3 = als[i3];
        float w0 = __expf(lrelu(a0 + aldn));
        float w1 = __expf(lrelu(a1 + aldn));
        float w2 = __expf(lrelu(a2 + aldn));
        float w3 = __expf(lrelu(a3 + aldn));
        s0x += w0 * f0.x; s0y += w0 * f0.y;
        s1x += w1 * f1.x; s1y += w1 * f1.y;
        s2x += w2 * f2.x; s2y += w2 * f2.y;
        s3x += w3 * f3.x; s3y += w3 * f3.y;
        den += (w0 + w1) + (w2 + w3);
    }
    for (; e < e1; ++e) {
        int s = csr_src[e];
        float we = __expf(lrelu(als[s] + aldn));
        float2 f = h2p[(size_t)s * 8 + l];
        s0x += we * f.x; s0y += we * f.y;
        den += we;
    }
    float inv = 1.0f / den;
    float2 r;
    r.x = (s0x + s1x + s2x + s3x) * inv + b2[2 * l];
    r.y = (s0y + s1y + s2y + s3y) * inv + b2[2 * l + 1];
    ((float2*)out)[(size_t)n * 8 + l] = r;
}

extern "C" void kernel_launch(void* const* d_in, const int* in_sizes, int n_in,
                              void* d_out, int out_size, void* d_ws, size_t ws_size,
                              hipStream_t stream)
{
    const float* x   = (const float*)d_in[0];
    const int*   ei  = (const int*)d_in[1];
    // d_in[2] = ew, unused (edge_dim=None)
    const float* W1  = (const float*)d_in[3];
    const float* as1 = (const float*)d_in[4];
    const float* ad1 = (const float*)d_in[5];
    const float* b1  = (const float*)d_in[6];
    const float* W2  = (const float*)d_in[7];
    const float* as2 = (const float*)d_in[8];
    const float* ad2 = (const float*)d_in[9];
    const float* b2  = (const float*)d_in[10];
    float* out = (float*)d_out;

    const int Nn = in_sizes[0] / FEAT;   // 100000
    const int E_ = in_sizes[1] / 2;      // 3200000
    const int nb = (Nn + BIN_NODES - 1) >> BSH;   // 391

    // workspace layout
    float* h1    = (float*)d_ws;                  // Nn*32 (also CSR-build scratch)
    float* als1  = h1 + (size_t)Nn * HID;         // Nn
    float* ald1  = als1 + Nn;                     // Nn
    float* h2    = ald1 + Nn;                     // Nn*16
    float* als2p = h2 + (size_t)Nn * EMB;         // Nn
    float* ald2p = als2p + Nn;                    // Nn
    int* rowptr  = (int*)(ald2p + Nn);            // Nn+1
    int* binCnt  = rowptr + Nn + 1;               // NBMAX
    int* binstart= binCnt + NBMAX;                // NBMAX+1
    int* bin_pos = binstart + NBMAX + 1;          // NBMAX
    int* packed  = bin_pos + NBMAX;               // E_  (becomes csr_src in place)
    // total: 52*Nn floats + (Nn+1+3*NBMAX+1+E_) ints ~= 34 MB

    // ---- build CSR (by destination) via binned counting sort ----
    k_zero_int<<<(nb + 255) / 256, 256, 0, stream>>>(binCnt, nb);
    k_bincnt<<<1024, 256, 0, stream>>>(ei, E_, Nn, binCnt);
    k_binscan<<<1, 512, 0, stream>>>(binCnt, binstart, bin_pos, rowptr, Nn, E_);
    k_part<<<(E_ + CH - 1) / CH, 1024, 0, stream>>>(ei, E_, Nn, bin_pos, packed);
    k_build<<<nb, 1024, 0, stream>>>(binstart, Nn, E_, packed, rowptr, (int*)h1);

    // ---- layer 1 ----
    k_h1<<<(Nn + 31) / 32, 256, 0, stream>>>(x, W1, as1, ad1, h1, als1, ald1, Nn);
    k_agg1<<<(Nn + 15) / 16, 256, 0, stream>>>(rowptr, packed, h1, als1, ald1,
                                               b1, W2, as2, ad2, h2, als2p, ald2p, Nn);
    // ---- layer 2 ----
    k_agg2<<<(Nn + 31) / 32, 256, 0, stream>>>(rowptr, packed, h2, als2p, ald2p,
                                               b2, out, Nn);
}

// Round 6
// 317.307 us; speedup vs baseline: 1.4641x; 1.1070x over previous
//
#include <hip/hip_runtime.h>

#define FEAT 128
#define HID 32
#define EMB 16
#define NEG 0.2f

// CSR-build binning parameters. Assumes Nn <= 2^17 (src id fits 17 bits) and
// Nn <= NBMAX*BIN_NODES. For this problem Nn=100000, E=3.2M.
#define BSH 8                 // 256 nodes per bin
#define BIN_NODES 256
#define NBMAX 400             // >= ceil(100000/256)=391
#define CH 8192               // edges per partition block
#define CAP 12288             // LDS staging capacity per bin (mean 8192, +45 sigma)
#define SRCBITS 17
#define SRCMASK 0x1FFFF

__device__ __forceinline__ float lrelu(float a) { return a > 0.0f ? a : NEG * a; }

__global__ __launch_bounds__(256) void k_zero_int(int* p, int n) {
    int i = (int)(blockIdx.x * 256 + threadIdx.x);
    if (i < n) p[i] = 0;
}

// ---- CSR build, phase 1: per-bin edge counts (dst >> BSH) ----
__global__ __launch_bounds__(256) void k_bincnt(const int* __restrict__ ei, int E_,
                                                int Nn, int* __restrict__ binCnt) {
    __shared__ int h[NBMAX];
    int nb = (Nn + BIN_NODES - 1) >> BSH;
    for (int i = threadIdx.x; i < nb; i += 256) h[i] = 0;
    __syncthreads();
    int stride = (int)(gridDim.x * 256);
    for (int i = (int)(blockIdx.x * 256 + threadIdx.x); i < E_; i += stride)
        atomicAdd(&h[ei[(size_t)E_ + i] >> BSH], 1);
    __syncthreads();
    for (int i = threadIdx.x; i < nb; i += 256)
        if (h[i]) atomicAdd(&binCnt[i], h[i]);
}

// ---- phase 2: scan bin counts -> binstart, init bin_pos; rowptr[Nn]=E ----
__global__ __launch_bounds__(512) void k_binscan(const int* __restrict__ binCnt,
                                                 int* __restrict__ binstart,
                                                 int* __restrict__ bin_pos,
                                                 int* __restrict__ rowptr,
                                                 int Nn, int E_) {
    __shared__ int s[512];
    int nb = (Nn + BIN_NODES - 1) >> BSH;
    int t = (int)threadIdx.x;
    s[t] = (t < nb) ? binCnt[t] : 0;
    __syncthreads();
    for (int off = 1; off < 512; off <<= 1) {
        int v = (t >= off) ? s[t - off] : 0;
        __syncthreads();
        s[t] += v;
        __syncthreads();
    }
    if (t <= nb) binstart[t] = (t == 0) ? 0 : s[t - 1];
    if (t < nb) bin_pos[t] = (t == 0) ? 0 : s[t - 1];
    if (t == 0) rowptr[Nn] = E_;
}

// ---- phase 3: multisplit partition. Stage chunk in LDS grouped by bin, then
// write contiguous per-bin runs of packed words ((dst&255)<<17 | src). ----
__global__ __launch_bounds__(1024) void k_part(const int* __restrict__ ei, int E_,
                                               int Nn, int* __restrict__ bin_pos,
                                               int* __restrict__ packed) {
    __shared__ int hist[NBMAX];
    __shared__ int lofs[NBMAX];
    __shared__ int pos[NBMAX];
    __shared__ int gbase[NBMAX];
    __shared__ int sscan[512];
    __shared__ int staged[CH];
    __shared__ unsigned short sbin[CH];
    int nb = (Nn + BIN_NODES - 1) >> BSH;
    int base = (int)(blockIdx.x * CH);
    int nE = min(CH, E_ - base);
    int t = (int)threadIdx.x;
    for (int i = t; i < nb; i += 1024) hist[i] = 0;
    __syncthreads();

    int myw[CH / 1024];
    int myb[CH / 1024];
#pragma unroll
    for (int k = 0; k < CH / 1024; ++k) {
        int i = t + k * 1024;
        int w = 0, b_ = -1;
        if (i < nE) {
            int s_ = ei[base + i];
            int d_ = ei[(size_t)E_ + base + i];
            b_ = d_ >> BSH;
            w = ((d_ & (BIN_NODES - 1)) << SRCBITS) | s_;
            atomicAdd(&hist[b_], 1);
        }
        myw[k] = w;
        myb[k] = b_;
    }
    __syncthreads();
    // exclusive scan of hist over 512-wide region
    if (t < 512) sscan[t] = (t < nb) ? hist[t] : 0;
    __syncthreads();
    for (int off = 1; off < 512; off <<= 1) {
        int v = 0;
        if (t < 512 && t >= off) v = sscan[t - off];
        __syncthreads();
        if (t < 512) sscan[t] += v;
        __syncthreads();
    }
    for (int i = t; i < nb; i += 1024) {
        int ex = (i == 0) ? 0 : sscan[i - 1];
        lofs[i] = ex;
        pos[i] = ex;
    }
    __syncthreads();
    // scatter into LDS grouped by bin
#pragma unroll
    for (int k = 0; k < CH / 1024; ++k) {
        if (myb[k] >= 0) {
            int p = atomicAdd(&pos[myb[k]], 1);
            staged[p] = myw[k];
            sbin[p] = (unsigned short)myb[k];
        }
    }
    __syncthreads();
    // reserve global runs (one atomic per non-empty bin)
    for (int i = t; i < nb; i += 1024)
        gbase[i] = hist[i] ? atomicAdd(&bin_pos[i], hist[i]) : 0;
    __syncthreads();
    // coalesced write-out of per-bin runs
    for (int i = t; i < nE; i += 1024) {
        int b_ = sbin[i];
        packed[gbase[b_] + (i - lofs[b_])] = staged[i];
    }
}

// ---- phase 4: per-bin build. LDS scatter -> coalesced CSR (in place over
// packed), and writes the bin's slice of rowptr. scratch = h1 buffer (free
// until k_h1 runs) used only in the (statistically impossible) overflow path.
__global__ __launch_bounds__(1024) void k_build(const int* __restrict__ binstart,
                                                int Nn, int E_,
                                                int* __restrict__ packed,
                                                int* __restrict__ rowptr,
                                                int* __restrict__ scratch) {
    __shared__ int ncnt[BIN_NODES];
    __shared__ int npos[BIN_NODES];
    __shared__ int sscan[BIN_NODES];
    __shared__ int csr_l[CAP];
    int b = (int)blockIdx.x;
    int s = binstart[b], e = binstart[b + 1];
    int cnt = e - s;
    int nb0 = b << BSH;
    int nodes = min(BIN_NODES, Nn - nb0);
    int t = (int)threadIdx.x;
    if (t < BIN_NODES) ncnt[t] = 0;
    __syncthreads();
    for (int i = t; i < cnt; i += 1024) atomicAdd(&ncnt[packed[s + i] >> SRCBITS], 1);
    __syncthreads();
    if (t < BIN_NODES) sscan[t] = ncnt[t];
    __syncthreads();
    for (int off = 1; off < BIN_NODES; off <<= 1) {
        int v = 0;
        if (t < BIN_NODES && t >= off) v = sscan[t - off];
        __syncthreads();
        if (t < BIN_NODES) sscan[t] += v;
        __syncthreads();
    }
    if (t < BIN_NODES) {
        int ex = (t == 0) ? 0 : sscan[t - 1];
        npos[t] = ex;
        if (t < nodes) rowptr[nb0 + t] = s + ex;
    }
    __syncthreads();
    if (cnt <= CAP) {
        for (int i = t; i < cnt; i += 1024) {
            int w = packed[s + i];
            int p = atomicAdd(&npos[w >> SRCBITS], 1);
            csr_l[p] = w & SRCMASK;
        }
        __syncthreads();
        for (int i = t; i < cnt; i += 1024) packed[s + i] = csr_l[i];
    } else {
        // overflow fallback: stage via global scratch, then in-place scatter
        for (int i = t; i < cnt; i += 1024) scratch[s + i] = packed[s + i];
        __syncthreads();
        for (int i = t; i < cnt; i += 1024) {
            int w = scratch[s + i];
            int p = atomicAdd(&npos[w >> SRCBITS], 1);
            packed[s + p] = w & SRCMASK;
        }
    }
}

// h1 = x @ W1 ; als/ald.  ONE ROW PER THREAD. x loads are per-lane float4 of
// the lane's own row (all bytes consumed by the wave within 4 iters, L2-hot).
// W1 accesses are wave-uniform -> compiler scalarizes to s_load, inner loop
// becomes v_fmac(v_acc, s_w, v_x): no LDS, no shuffles, no syncthreads.
__global__ __launch_bounds__(256) void k_h1(
    const float* __restrict__ x, const float* __restrict__ W1,
    const float* __restrict__ a_s, const float* __restrict__ a_d,
    float* __restrict__ h1, float* __restrict__ als, float* __restrict__ ald, int Nn)
{
    int row = (int)(blockIdx.x * 256 + threadIdx.x);
    if (row >= Nn) return;
    const float4* xr = (const float4*)(x + (size_t)row * FEAT);
    float acc[HID];
#pragma unroll
    for (int c = 0; c < HID; ++c) acc[c] = 0.0f;
#pragma unroll 4
    for (int k4 = 0; k4 < FEAT / 4; ++k4) {
        float4 xv = xr[k4];
        const float* Wr = W1 + k4 * 4 * HID;   // wave-uniform -> s_load
#pragma unroll
        for (int c = 0; c < HID; ++c)
            acc[c] += xv.x * Wr[c] + xv.y * Wr[HID + c]
                    + xv.z * Wr[2 * HID + c] + xv.w * Wr[3 * HID + c];
    }
    float4* hr = (float4*)(h1 + (size_t)row * HID);
    float ps = 0.0f, pd = 0.0f;
#pragma unroll
    for (int c4 = 0; c4 < HID / 4; ++c4) {
        float4 hv;
        hv.x = acc[4 * c4 + 0]; hv.y = acc[4 * c4 + 1];
        hv.z = acc[4 * c4 + 2]; hv.w = acc[4 * c4 + 3];
        hr[c4] = hv;
        ps += hv.x * a_s[4 * c4 + 0] + hv.y * a_s[4 * c4 + 1]
            + hv.z * a_s[4 * c4 + 2] + hv.w * a_s[4 * c4 + 3];
        pd += hv.x * a_d[4 * c4 + 0] + hv.y * a_d[4 * c4 + 1]
            + hv.z * a_d[4 * c4 + 2] + hv.w * a_d[4 * c4 + 3];
    }
    als[row] = ps;
    ald[row] = pd;
}

// layer-1 gather-aggregate + norm + relu + (g @ W2) + als2/ald2, fused.
// 16 lanes per node, each lane owns 2 features (float2). Edge loop unrolled
// 4x: four independent gather chains in flight; edge weights computed
// redundantly per lane (identical across group -> den needs no reduction).
__global__ __launch_bounds__(256) void k_agg1(
    const int* __restrict__ rowptr, const int* __restrict__ csr_src,
    const float* __restrict__ h1, const float* __restrict__ als,
    const float* __restrict__ ald, const float* __restrict__ b1,
    const float* __restrict__ W2, const float* __restrict__ a_s2,
    const float* __restrict__ a_d2,
    float* __restrict__ h2, float* __restrict__ als2, float* __restrict__ ald2, int Nn)
{
    int n = (int)(blockIdx.x * 16 + (threadIdx.x >> 4));
    if (n >= Nn) return;
    int l = threadIdx.x & 15;                  // lane in 16-lane group
    const float2* h1p = (const float2*)h1;     // row s = elems [s*16 .. s*16+15]
    float aldn = ald[n];
    float wself = __expf(lrelu(als[n] + aldn));
    float2 sv = h1p[(size_t)n * 16 + l];
    float s0x = wself * sv.x, s0y = wself * sv.y;
    float s1x = 0, s1y = 0, s2x = 0, s2y = 0, s3x = 0, s3y = 0;
    float den = wself;
    int e = rowptr[n], e1 = rowptr[n + 1];
    for (; e + 4 <= e1; e += 4) {
        int i0 = csr_src[e + 0];
        int i1 = csr_src[e + 1];
        int i2 = csr_src[e + 2];
        int i3 = csr_src[e + 3];
        float2 f0 = h1p[(size_t)i0 * 16 + l];
        float2 f1 = h1p[(size_t)i1 * 16 + l];
        float2 f2 = h1p[(size_t)i2 * 16 + l];
        float2 f3 = h1p[(size_t)i3 * 16 + l];
        float a0 = als[i0], a1 = als[i1], a2 = als[i2], a3 = als[i3];
        float w0 = __expf(lrelu(a0 + aldn));
        float w1 = __expf(lrelu(a1 + aldn));
        float w2 = __expf(lrelu(a2 + aldn));
        float w3 = __expf(lrelu(a3 + aldn));
        s0x += w0 * f0.x; s0y += w0 * f0.y;
        s1x += w1 * f1.x; s1y += w1 * f1.y;
        s2x += w2 * f2.x; s2y += w2 * f2.y;
        s3x += w3 * f3.x; s3y += w3 * f3.y;
        den += (w0 + w1) + (w2 + w3);
    }
    for (; e < e1; ++e) {
        int s = csr_src[e];
        float we = __expf(lrelu(als[s] + aldn));
        float2 f = h1p[(size_t)s * 16 + l];
        s0x += we * f.x; s0y += we * f.y;
        den += we;
    }
    float inv = 1.0f / den;
    float gx = fmaxf((s0x + s1x + s2x + s3x) * inv + b1[2 * l], 0.0f);
    float gy = fmaxf((s0y + s1y + s2y + s3y) * inv + b1[2 * l + 1], 0.0f);
    // h2[n][j] = sum_t g[t] * W2[t][j], j = l; lane tt holds feats 2tt,2tt+1
    float hc = 0.0f;
#pragma unroll
    for (int tt = 0; tt < 16; ++tt) {
        float bx = __shfl(gx, tt, 16);
        float by = __shfl(gy, tt, 16);
        hc += bx * W2[(2 * tt) * EMB + l] + by * W2[(2 * tt + 1) * EMB + l];
    }
    h2[(size_t)n * EMB + l] = hc;
    float ps = hc * a_s2[l], pd = hc * a_d2[l];
    for (int m = 1; m < 16; m <<= 1) {
        ps += __shfl_xor(ps, m, 16);
        pd += __shfl_xor(pd, m, 16);
    }
    if (l == 0) { als2[n] = ps; ald2[n] = pd; }
}

// layer-2 gather-aggregate + bias. 8 lanes per node, float2 features, same
// unrolled independent-gather structure. Writes out as float2.
__global__ __launch_bounds__(256) void k_agg2(
    const int* __restrict__ rowptr, const int* __restrict__ csr_src,
    const float* __restrict__ h2, const float* __restrict__ als,
    const float* __restrict__ ald, const float* __restrict__ b2,
    float* __restrict__ out, int Nn)
{
    int n = (int)(blockIdx.x * 32 + (threadIdx.x >> 3));
    if (n >= Nn) return;
    int l = threadIdx.x & 7;                   // lane in 8-lane group
    const float2* h2p = (const float2*)h2;     // row s = elems [s*8 .. s*8+7]
    float aldn = ald[n];
    float wself = __expf(lrelu(als[n] + aldn));
    float2 sv = h2p[(size_t)n * 8 + l];
    float s0x = wself * sv.x, s0y = wself * sv.y;
    float s1x = 0, s1y = 0, s2x = 0, s2y = 0, s3x = 0, s3y = 0;
    float den = wself;
    int e = rowptr[n], e1 = rowptr[n + 1];
    for (; e + 4 <= e1; e += 4) {
        int i0 = csr_src[e + 0];
        int i1 = csr_src[e + 1];
        int i2 = csr_src[e + 2];
        int i3 = csr_src[e + 3];
        float2 f0 = h2p[(size_t)i0 * 8 + l];
        float2 f1 = h2p[(size_t)i1 * 8 + l];
        float2 f2 = h2p[(size_t)i2 * 8 + l];
        float2 f3 = h2p[(size_t)i3 * 8 + l];
        float a0 = als[i0], a1 = als[i1], a2 = als[i2], a3 = als[i3];
        float w0 = __expf(lrelu(a0 + aldn));
        float w1 = __expf(lrelu(a1 + aldn));
        float w2 = __expf(lrelu(a2 + aldn));
        float w3 = __expf(lrelu(a3 + aldn));
        s0x += w0 * f0.x; s0y += w0 * f0.y;
        s1x += w1 * f1.x; s1y += w1 * f1.y;
        s2x += w2 * f2.x; s2y += w2 * f2.y;
        s3x += w3 * f3.x; s3y += w3 * f3.y;
        den += (w0 + w1) + (w2 + w3);
    }
    for (; e < e1; ++e) {
        int s = csr_src[e];
        float we = __expf(lrelu(als[s] + aldn));
        float2 f = h2p[(size_t)s * 8 + l];
        s0x += we * f.x; s0y += we * f.y;
        den += we;
    }
    float inv = 1.0f / den;
    float2 r;
    r.x = (s0x + s1x + s2x + s3x) * inv + b2[2 * l];
    r.y = (s0y + s1y + s2y + s3y) * inv + b2[2 * l + 1];
    ((float2*)out)[(size_t)n * 8 + l] = r;
}

extern "C" void kernel_launch(void* const* d_in, const int* in_sizes, int n_in,
                              void* d_out, int out_size, void* d_ws, size_t ws_size,
                              hipStream_t stream)
{
    const float* x   = (const float*)d_in[0];
    const int*   ei  = (const int*)d_in[1];
    // d_in[2] = ew, unused (edge_dim=None)
    const float* W1  = (const float*)d_in[3];
    const float* as1 = (const float*)d_in[4];
    const float* ad1 = (const float*)d_in[5];
    const float* b1  = (const float*)d_in[6];
    const float* W2  = (const float*)d_in[7];
    const float* as2 = (const float*)d_in[8];
    const float* ad2 = (const float*)d_in[9];
    const float* b2  = (const float*)d_in[10];
    float* out = (float*)d_out;

    const int Nn = in_sizes[0] / FEAT;   // 100000
    const int E_ = in_sizes[1] / 2;      // 3200000
    const int nb = (Nn + BIN_NODES - 1) >> BSH;   // 391

    // workspace layout
    float* h1    = (float*)d_ws;                  // Nn*32 (also CSR-build scratch)
    float* als1  = h1 + (size_t)Nn * HID;         // Nn
    float* ald1  = als1 + Nn;                     // Nn
    float* h2    = ald1 + Nn;                     // Nn*16
    float* als2p = h2 + (size_t)Nn * EMB;         // Nn
    float* ald2p = als2p + Nn;                    // Nn
    int* rowptr  = (int*)(ald2p + Nn);            // Nn+1
    int* binCnt  = rowptr + Nn + 1;               // NBMAX
    int* binstart= binCnt + NBMAX;                // NBMAX+1
    int* bin_pos = binstart + NBMAX + 1;          // NBMAX
    int* packed  = bin_pos + NBMAX;               // E_  (becomes csr_src in place)
    // total: 52*Nn floats + (Nn+1+3*NBMAX+1+E_) ints ~= 34 MB

    // ---- build CSR (by destination) via binned counting sort ----
    k_zero_int<<<(nb + 255) / 256, 256, 0, stream>>>(binCnt, nb);
    k_bincnt<<<1024, 256, 0, stream>>>(ei, E_, Nn, binCnt);
    k_binscan<<<1, 512, 0, stream>>>(binCnt, binstart, bin_pos, rowptr, Nn, E_);
    k_part<<<(E_ + CH - 1) / CH, 1024, 0, stream>>>(ei, E_, Nn, bin_pos, packed);
    k_build<<<nb, 1024, 0, stream>>>(binstart, Nn, E_, packed, rowptr, (int*)h1);

    // ---- layer 1 ----
    k_h1<<<(Nn + 255) / 256, 256, 0, stream>>>(x, W1, as1, ad1, h1, als1, ald1, Nn);
    k_agg1<<<(Nn + 15) / 16, 256, 0, stream>>>(rowptr, packed, h1, als1, ald1,
                                               b1, W2, as2, ad2, h2, als2p, ald2p, Nn);
    // ---- layer 2 ----
    k_agg2<<<(Nn + 31) / 32, 256, 0, stream>>>(rowptr, packed, h2, als2p, ald2p,
                                               b2, out, Nn);
}